// Round 13
// baseline (499.757 us; speedup 1.0000x reference)
//
#include <hip/hip_runtime.h>

// CausalSelfAttention: B=2, T=4096, E=768, H=12, D=64
// prep -> QKV GEMM (m97-style, C^T epilogue) ->
// chunked flash attention (r7-exact body, launch_bounds(256,5) for 5 blocks/CU) ->
// merge partials -> proj GEMM
// FROZEN LESSONS:
//  - attn body needs ~96 unified regs (64 arch VGPR + 32 AGPR acc). Cap < 96
//    (launch_bounds arg >= 6 -> cap 80) spills accumulators -> ~3.3 GB scratch,
//    6x regression (r6, r10; VGPR_Count=40 signature). Arg 5 -> cap 102 >= 96: safe.
//  - r8 (reg-prefetch dbuf) and r9 (no-max softmax) regressed via codegen-induced
//    scratch/remat traffic. Keep the r7 attn body byte-frozen.
//  - r12: kv-step 128 (half the barriers) was NEUTRAL -> barriers are not the
//    binding constraint; residency is. Hence this round: (256,5) + 18.4 KB LDS.

#define SEQT 4096
#define EMB  768
#define NHEAD 12
#define HDIM 64
#define NCHUNK 144   // sum over qt of ceil((qt+1)/4)

typedef __attribute__((ext_vector_type(8))) short bf16x8;
typedef __attribute__((ext_vector_type(4))) float f32x4;
typedef __attribute__((ext_vector_type(16))) float f32x16;

static __device__ __forceinline__ unsigned short f2bf(float f) {
  union { float f; unsigned u; } a; a.f = f;
  unsigned u = a.u;
  u += 0x7FFF + ((u >> 16) & 1);   // RNE
  return (unsigned short)(u >> 16);
}

// pack two f32 -> bf16x2 {lo=a, hi=b} via v_perm_b32 (verified round 4)
static __device__ __forceinline__ unsigned pack_bf16(float a, float b) {
  union { float f; unsigned u; } ua, ub; ua.f = a; ub.f = b;
  return __builtin_amdgcn_perm(ub.u + 0x8000u, ua.u + 0x8000u, 0x07060302u);
}

static __device__ __forceinline__ void gload_lds16(const short* g, short* l) {
  __builtin_amdgcn_global_load_lds(
      (const __attribute__((address_space(1))) unsigned*)(const void*)g,
      (__attribute__((address_space(3))) unsigned*)(void*)l, 16, 0, 0);
}

// ---------------- prep ----------------
__global__ __launch_bounds__(256) void cast_bf16_kernel(
    const float* __restrict__ in, short* __restrict__ out, int n4) {
  int i = blockIdx.x * 256 + threadIdx.x;
  if (i >= n4) return;
  float4 v = ((const float4*)in)[i];
  ushort4 o;
  o.x = f2bf(v.x); o.y = f2bf(v.y); o.z = f2bf(v.z); o.w = f2bf(v.w);
  ((ushort4*)out)[i] = o;
}

__global__ __launch_bounds__(256) void transpose_bf16_kernel(
    const float* __restrict__ in, short* __restrict__ out, int R, int C) {
  __shared__ float tile[32][33];
  int c0 = blockIdx.x * 32, r0 = blockIdx.y * 32;
  int tx = threadIdx.x, ty = threadIdx.y;   // 32 x 8
#pragma unroll
  for (int j = 0; j < 32; j += 8)
    tile[ty + j][tx] = in[(size_t)(r0 + ty + j) * C + (c0 + tx)];
  __syncthreads();
#pragma unroll
  for (int j = 0; j < 32; j += 8)
    out[(size_t)(c0 + ty + j) * R + (r0 + tx)] = (short)f2bf(tile[tx][ty + j]);
}

// ---------------- GEMM (m97-style): 128x128 tile, 4 waves, BK=32, global_load_lds ----
// MODE 0: QKV, C^T in regs (mfma(B,A)) -> packed Q/K stores + Vt scatter
// MODE 1: proj, C in regs -> fp32 out [M][768]
template <int MODE>
__global__ __launch_bounds__(256) void gemm128_kernel(
    const short* __restrict__ A, const short* __restrict__ Bt,
    const float* __restrict__ bias, int K,
    short* __restrict__ Qg, short* __restrict__ Kg, short* __restrict__ Vtg,
    float* __restrict__ Out) {
  __shared__ short As[128 * 32];
  __shared__ short Bs[128 * 32];
  int tid = threadIdx.x;
  int w = tid >> 6, l = tid & 63, quad = l >> 4, lo = l & 15;
  int wm = (w >> 1) * 64, wn = (w & 1) * 64;
  int gm = blockIdx.x, gn = blockIdx.y;
  f32x4 acc[4][4] = {};
  int c0 = tid, c1 = tid + 256;   // 16B chunks: row=c>>2, k-sub=(c&3)*8
  const short* Ag0 = A + (size_t)(gm * 128 + (c0 >> 2)) * K + (c0 & 3) * 8;
  const short* Ag1 = A + (size_t)(gm * 128 + (c1 >> 2)) * K + (c1 & 3) * 8;
  const short* Bg0 = Bt + (size_t)(gn * 128 + (c0 >> 2)) * K + (c0 & 3) * 8;
  const short* Bg1 = Bt + (size_t)(gn * 128 + (c1 >> 2)) * K + (c1 & 3) * 8;

  for (int kk = 0; kk < K; kk += 32) {
    gload_lds16(Ag0 + kk, &As[c0 * 8]);
    gload_lds16(Ag1 + kk, &As[c1 * 8]);
    gload_lds16(Bg0 + kk, &Bs[c0 * 8]);
    gload_lds16(Bg1 + kk, &Bs[c1 * 8]);
    __syncthreads();
    bf16x8 af[4], bf[4];
#pragma unroll
    for (int mt = 0; mt < 4; mt++)
      af[mt] = *(const bf16x8*)&As[(wm + mt * 16 + lo) * 32 + quad * 8];
#pragma unroll
    for (int nt = 0; nt < 4; nt++)
      bf[nt] = *(const bf16x8*)&Bs[(wn + nt * 16 + lo) * 32 + quad * 8];
#pragma unroll
    for (int mt = 0; mt < 4; mt++)
#pragma unroll
      for (int nt = 0; nt < 4; nt++) {
        if (MODE == 0)   // C^T: reg-dim = n, lane-dim = m
          acc[mt][nt] = __builtin_amdgcn_mfma_f32_16x16x32_bf16(bf[nt], af[mt], acc[mt][nt], 0, 0, 0);
        else
          acc[mt][nt] = __builtin_amdgcn_mfma_f32_16x16x32_bf16(af[mt], bf[nt], acc[mt][nt], 0, 0, 0);
      }
    __syncthreads();
  }

  if (MODE == 0) {
#pragma unroll
    for (int nt = 0; nt < 4; nt++) {
      int nb = gn * 128 + wn + nt * 16 + quad * 4;   // 4 consecutive n in regs
      float4 bv = *(const float4*)&bias[nb];
#pragma unroll
      for (int mt = 0; mt < 4; mt++) {
        int m = gm * 128 + wm + mt * 16 + lo;
        int b = m >> 12, t = m & 4095;
        float v0 = acc[mt][nt][0] + bv.x;
        float v1 = acc[mt][nt][1] + bv.y;
        float v2 = acc[mt][nt][2] + bv.z;
        float v3 = acc[mt][nt][3] + bv.w;
        if (nb < EMB) {
          int h = nb >> 6, d = nb & 63;
          uint2 u; u.x = pack_bf16(v0, v1); u.y = pack_bf16(v2, v3);
          *(uint2*)&Qg[(((size_t)b * NHEAD + h) * SEQT + t) * HDIM + d] = u;
        } else if (nb < 2 * EMB) {
          int n2 = nb - EMB, h = n2 >> 6, d = n2 & 63;
          uint2 u; u.x = pack_bf16(v0, v1); u.y = pack_bf16(v2, v3);
          *(uint2*)&Kg[(((size_t)b * NHEAD + h) * SEQT + t) * HDIM + d] = u;
        } else {
          int n2 = nb - 2 * EMB, h = n2 >> 6, d = n2 & 63;
          short* vp = &Vtg[(((size_t)b * NHEAD + h) * HDIM + d) * SEQT + t];
          vp[0] = (short)f2bf(v0);
          vp[SEQT] = (short)f2bf(v1);
          vp[2 * SEQT] = (short)f2bf(v2);
          vp[3 * SEQT] = (short)f2bf(v3);
        }
      }
    }
  } else {
#pragma unroll
    for (int nt = 0; nt < 4; nt++) {
      int n = gn * 128 + wn + nt * 16 + lo;
      float bias_v = bias[n];
#pragma unroll
      for (int mt = 0; mt < 4; mt++) {
#pragma unroll
        for (int r = 0; r < 4; r++) {
          int m = gm * 128 + wm + mt * 16 + quad * 4 + r;
          Out[(size_t)m * EMB + n] = acc[mt][nt][r] + bias_v;
        }
      }
    }
  }
}

// ---------------- flash attention (r7-exact body): chunked kv ----------------
// Grid (144, 24): blockIdx.x = chunk (qt desc, p asc), blockIdx.y = bh.
// Chunk = up to 8 kv-steps of 64 (512 kv). q-tile 128 (wave owns 32 q).
// launch_bounds (256,5): VGPR cap floor(512/5)=102 >= the 96 unified regs this
// body uses (64 arch + 32 acc) -> no spill; enables 5 blocks/CU (LDS 18.4KB*5=92KB ok).
// DO NOT go to 6 (cap 80 < 96 -> spill, r6/r10).
#define AP 72
#define NEG_BIG (-1e9f)
__global__ __launch_bounds__(256, 5) void attn_kernel(
    const short* __restrict__ Qg, const short* __restrict__ Kg,
    const short* __restrict__ Vtg, short* __restrict__ Opart,
    float2* __restrict__ Ml) {
  __shared__ short Ks[64 * AP];   // [kv][d]
  __shared__ short Vs[64 * AP];   // [d][kv]
  int tid = threadIdx.x;
  int w = tid >> 6, l = tid & 63;
  int li = l & 31, hi = l >> 5;
  int c = blockIdx.x;
  int bh = blockIdx.y;
  // map c -> (qt desc, p): nc(qt) = ceil((qt+1)/4) = (qt+4)>>2
  int qt = 31, rem = c;
  while (rem >= ((qt + 4) >> 2)) { rem -= (qt + 4) >> 2; qt--; }
  int p = rem;
  int q0 = qt * 128;
  int cid = bh * NCHUNK + c;
  const short* Qbase = Qg + (size_t)bh * SEQT * HDIM;
  const short* Kbase = Kg + (size_t)bh * SEQT * HDIM;
  const short* Vbase = Vtg + (size_t)bh * HDIM * SEQT;

  int qw = q0 + w * 32;            // wave's 32 q rows
  // Q B-frags: n=li -> q=qw+li, k=hi*8+j -> d=kk*16+hi*8+j
  bf16x8 qf[4];
#pragma unroll
  for (int kk = 0; kk < 4; kk++)
    qf[kk] = *(const bf16x8*)&Qbase[(size_t)(qw + li) * HDIM + kk * 16 + hi * 8];

  f32x16 O[2] = {};                // O^T[dt]: d=dt*32+(reg&3)+8*(reg>>2)+4hi, q=qw+li
  float m_s = NEG_BIG;
  float l_s = 0.f;

  int sr = tid >> 2, sc = tid & 3;
  const float SC = 0.18033688011112042f;   // (1/8) * log2(e)
  int s_begin = 8 * p;
  int s_end = min(8 * p + 8, 2 * qt + 2);

  for (int s = s_begin; s < s_end; s++) {
    int kv0 = s * 64;
    // stage K (row-major [kv][64]) and Vt ([d][kv]) tiles
    const short* kg = &Kbase[(size_t)(kv0 + sr) * HDIM + sc * 8];
    const short* vg = &Vbase[(size_t)sr * SEQT + kv0 + sc * 8];
    uint4 k0 = *(const uint4*)kg;
    uint4 k1 = *(const uint4*)(kg + 32);
    uint4 v0 = *(const uint4*)vg;
    uint4 v1 = *(const uint4*)(vg + 32);
    *(uint4*)&Ks[sr * AP + sc * 8] = k0;
    *(uint4*)&Ks[sr * AP + sc * 8 + 32] = k1;
    *(uint4*)&Vs[sr * AP + sc * 8] = v0;
    *(uint4*)&Vs[sr * AP + sc * 8 + 32] = v1;
    __syncthreads();

    if (kv0 <= qw) {                     // wave has work this step
      bool act1 = (kv0 + 32 <= qw);
      // K A-frags: m=kv-in-tile=li, k=hi*8+j -> d=kk*16+hi*8+j
      bf16x8 ka0[4], ka1[4];
#pragma unroll
      for (int kk = 0; kk < 4; kk++)
        ka0[kk] = *(const bf16x8*)&Ks[li * AP + kk * 16 + hi * 8];
      if (act1) {
#pragma unroll
        for (int kk = 0; kk < 4; kk++)
          ka1[kk] = *(const bf16x8*)&Ks[(32 + li) * AP + kk * 16 + hi * 8];
      }

      f32x16 st[2];
      {
        f32x16 a = {};
#pragma unroll
        for (int kk = 0; kk < 4; kk++)
          a = __builtin_amdgcn_mfma_f32_32x32x16_bf16(ka0[kk], qf[kk], a, 0, 0, 0);
        st[0] = a;
      }
      if (act1) {
        f32x16 a = {};
#pragma unroll
        for (int kk = 0; kk < 4; kk++)
          a = __builtin_amdgcn_mfma_f32_32x32x16_bf16(ka1[kk], qf[kk], a, 0, 0, 0);
        st[1] = a;
      }

      // online softmax (q = qw+li per lane; kv dim spans regs + hi halves)
      bool full0 = (kv0 < qw);
      float mx = NEG_BIG;
      if (full0) {
#pragma unroll
        for (int r = 0; r < 16; r++) mx = fmaxf(mx, st[0][r]);
      } else {                             // diagonal: R <= li-4hi
        int thr = li - 4 * hi;
#pragma unroll
        for (int r = 0; r < 16; r++) {
          const int R = (r & 3) + 8 * (r >> 2);
          st[0][r] = (R <= thr) ? st[0][r] : NEG_BIG;
          mx = fmaxf(mx, st[0][r]);
        }
      }
      if (act1) {
        bool full1 = (kv0 + 32 < qw);
        if (full1) {
#pragma unroll
          for (int r = 0; r < 16; r++) mx = fmaxf(mx, st[1][r]);
        } else {
          int thr = li - 4 * hi;           // qw-(kv0+32)=0 on diagonal
#pragma unroll
          for (int r = 0; r < 16; r++) {
            const int R = (r & 3) + 8 * (r >> 2);
            st[1][r] = (R <= thr) ? st[1][r] : NEG_BIG;
            mx = fmaxf(mx, st[1][r]);
          }
        }
      }
      mx = fmaxf(mx, __shfl_xor(mx, 32));
      float mn = fmaxf(m_s, mx);
      float c1 = SC * mn;
      float al = __builtin_amdgcn_exp2f(fminf(SC * m_s - c1, 0.f));
      m_s = mn;
      float sm = 0.f;
      unsigned pk[2][8];
#pragma unroll
      for (int r2 = 0; r2 < 8; r2++) {
        float pa = __builtin_amdgcn_exp2f(fminf(__builtin_fmaf(st[0][2 * r2],     SC, -c1), 0.f));
        float pb = __builtin_amdgcn_exp2f(fminf(__builtin_fmaf(st[0][2 * r2 + 1], SC, -c1), 0.f));
        sm += pa + pb;
        pk[0][r2] = pack_bf16(pa, pb);
      }
      if (act1) {
#pragma unroll
        for (int r2 = 0; r2 < 8; r2++) {
          float pa = __builtin_amdgcn_exp2f(fminf(__builtin_fmaf(st[1][2 * r2],     SC, -c1), 0.f));
          float pb = __builtin_amdgcn_exp2f(fminf(__builtin_fmaf(st[1][2 * r2 + 1], SC, -c1), 0.f));
          sm += pa + pb;
          pk[1][r2] = pack_bf16(pa, pb);
        }
      }
      sm += __shfl_xor(sm, 32);
      l_s = l_s * al + sm;
#pragma unroll
      for (int dt = 0; dt < 2; dt++)
#pragma unroll
        for (int r = 0; r < 16; r++) O[dt][r] *= al;

      // PV: B-frag built in-register from C/D regs; one cross-half exchange
#pragma unroll
      for (int g = 0; g < 4; g++) {
        int t = g >> 1, k2 = g & 1;
        if (t == 1 && !act1) continue;
        unsigned own_a = hi ? pk[t][k2 * 4 + 2] : pk[t][k2 * 4 + 0];
        unsigned own_b = hi ? pk[t][k2 * 4 + 3] : pk[t][k2 * 4 + 1];
        unsigned snd_a = hi ? pk[t][k2 * 4 + 0] : pk[t][k2 * 4 + 2];
        unsigned snd_b = hi ? pk[t][k2 * 4 + 1] : pk[t][k2 * 4 + 3];
        unsigned rcv_a = (unsigned)__shfl_xor((int)snd_a, 32);
        unsigned rcv_b = (unsigned)__shfl_xor((int)snd_b, 32);
        union { unsigned u[4]; bf16x8 v; } pf;
        pf.u[0] = hi ? rcv_a : own_a;
        pf.u[1] = hi ? rcv_b : own_b;
        pf.u[2] = hi ? own_a : rcv_a;
        pf.u[3] = hi ? own_b : rcv_b;
        // V A-frags loaded lazily (short live range)
        bf16x8 va0 = *(const bf16x8*)&Vs[li * AP + g * 16 + hi * 8];
        bf16x8 va1 = *(const bf16x8*)&Vs[(32 + li) * AP + g * 16 + hi * 8];
        O[0] = __builtin_amdgcn_mfma_f32_32x32x16_bf16(va0, pf.v, O[0], 0, 0, 0);
        O[1] = __builtin_amdgcn_mfma_f32_32x32x16_bf16(va1, pf.v, O[1], 0, 0, 0);
      }
    }
    __syncthreads();
  }

  // epilogue: unnormalized O^T partial -> Opart[cid][lq][d] (bf16); (m,l) -> Ml
  int lq = w * 32 + li;
  short* op = &Opart[((size_t)cid * 128 + lq) * 64];
#pragma unroll
  for (int dt = 0; dt < 2; dt++) {
#pragma unroll
    for (int rg = 0; rg < 4; rg++) {
      uint2 u2;
      u2.x = pack_bf16(O[dt][rg * 4 + 0], O[dt][rg * 4 + 1]);
      u2.y = pack_bf16(O[dt][rg * 4 + 2], O[dt][rg * 4 + 3]);
      *(uint2*)(op + dt * 32 + rg * 8 + hi * 4) = u2;
    }
  }
  if (hi == 0) {
    float2 ml; ml.x = m_s; ml.y = l_s;
    Ml[(size_t)cid * 128 + lq] = ml;
  }
}

// ---------------- merge partials ----------------
// Grid (32, 24): qt, bh. 256 thr: lq=tid>>1 (128 q), half=tid&1 (32 d each).
__global__ __launch_bounds__(256) void merge_kernel(
    const short* __restrict__ Opart, const float2* __restrict__ Ml,
    short* __restrict__ Y) {
  int qt = blockIdx.x, bh = blockIdx.y;
  int n = (qt + 4) >> 2;
  int cbase = 0;
  for (int j = qt + 1; j < 32; j++) cbase += (j + 4) >> 2;   // qt-desc layout
  int tid = threadIdx.x;
  int lq = tid >> 1, half = tid & 1;
  int b = bh / NHEAD, h = bh % NHEAD;
  int q = qt * 128 + lq;
  const float SC = 0.18033688011112042f;

  float m_i[8], l_i[8];
  float mstar = NEG_BIG;
#pragma unroll 4
  for (int i = 0; i < n; i++) {
    float2 ml = Ml[((size_t)bh * NCHUNK + cbase + i) * 128 + lq];
    m_i[i] = ml.x; l_i[i] = ml.y;
    mstar = fmaxf(mstar, ml.x);
  }
  float lstar = 0.f;
  float wgt[8];
#pragma unroll 4
  for (int i = 0; i < n; i++) {
    wgt[i] = __builtin_amdgcn_exp2f(fminf(SC * (m_i[i] - mstar), 0.f));
    lstar += l_i[i] * wgt[i];
  }

  float acc[32] = {};
#pragma unroll 4
  for (int i = 0; i < n; i++) {
    const short* op = &Opart[(((size_t)bh * NCHUNK + cbase + i) * 128 + lq) * 64 + half * 32];
    float wi = wgt[i];
#pragma unroll
    for (int v = 0; v < 4; v++) {
      uint4 u = ((const uint4*)op)[v];
      unsigned uu[4] = {u.x, u.y, u.z, u.w};
#pragma unroll
      for (int j = 0; j < 4; j++) {
        union { unsigned u; float f; } lo2, hi2;
        lo2.u = uu[j] << 16;
        hi2.u = uu[j] & 0xFFFF0000u;
        acc[v * 8 + j * 2]     = __builtin_fmaf(lo2.f, wi, acc[v * 8 + j * 2]);
        acc[v * 8 + j * 2 + 1] = __builtin_fmaf(hi2.f, wi, acc[v * 8 + j * 2 + 1]);
      }
    }
  }
  float rl = 1.f / lstar;
  short* yp = &Y[((size_t)b * SEQT + q) * EMB + h * 64 + half * 32];
#pragma unroll
  for (int v = 0; v < 4; v++) {
    uint2 u2;
    u2.x = pack_bf16(acc[v * 8 + 0] * rl, acc[v * 8 + 1] * rl);
    u2.y = pack_bf16(acc[v * 8 + 2] * rl, acc[v * 8 + 3] * rl);
    uint2 u3;
    u3.x = pack_bf16(acc[v * 8 + 4] * rl, acc[v * 8 + 5] * rl);
    u3.y = pack_bf16(acc[v * 8 + 6] * rl, acc[v * 8 + 7] * rl);
    *(uint2*)(yp + v * 8) = u2;
    *(uint2*)(yp + v * 8 + 4) = u3;
  }
}

extern "C" void kernel_launch(void* const* d_in, const int* in_sizes, int n_in,
                              void* d_out, int out_size, void* d_ws, size_t ws_size,
                              hipStream_t stream) {
  const float* x      = (const float*)d_in[0];   // [2,4096,768]
  const float* W_attn = (const float*)d_in[1];   // [768,2304]
  const float* b_attn = (const float*)d_in[2];   // [2304]
  const float* W_proj = (const float*)d_in[3];   // [768,768]
  const float* b_proj = (const float*)d_in[4];   // [768]
  float* out = (float*)d_out;                    // [2,4096,768] fp32

  char* ws = (char*)d_ws;
  short* x_bf  = (short*)(ws + 0);           // 8192x768 bf16
  short* Wt_a  = (short*)(ws + 12582912);    // 2304x768 bf16
  short* Wt_p  = (short*)(ws + 16121856);    // 768x768  bf16
  short* Qg    = (short*)(ws + 17301504);    // [2,12,4096,64]
  short* Kg    = (short*)(ws + 29884416);    // [2,12,4096,64]
  short* Vtg   = (short*)(ws + 42467328);    // [2,12,64,4096]
  short* Ybf   = (short*)(ws + 55050240);    // 8192x768 bf16
  short* Opart = (short*)(ws + 67633152);    // 3456 x 128 x 64 bf16 = 56,623,104 B
  float2* Ml   = (float2*)(ws + 124256256);  // 3456 x 128 float2 = 3,538,944 B
  // total 127,795,200 B

  cast_bf16_kernel<<<6144, 256, 0, stream>>>(x, x_bf, 1572864);
  transpose_bf16_kernel<<<dim3(72, 24), dim3(32, 8), 0, stream>>>(W_attn, Wt_a, 768, 2304);
  transpose_bf16_kernel<<<dim3(24, 24), dim3(32, 8), 0, stream>>>(W_proj, Wt_p, 768, 768);

  gemm128_kernel<0><<<dim3(64, 18), 256, 0, stream>>>(x_bf, Wt_a, b_attn, 768,
                                                      Qg, Kg, Vtg, nullptr);
  attn_kernel<<<dim3(NCHUNK, 24), 256, 0, stream>>>(Qg, Kg, Vtg, Opart, Ml);
  merge_kernel<<<dim3(32, 24), 256, 0, stream>>>(Opart, Ml, Ybf);
  gemm128_kernel<1><<<dim3(64, 6), 256, 0, stream>>>(Ybf, Wt_p, b_proj, 768,
                                                     nullptr, nullptr, nullptr, out);
}

// Round 14
// 344.995 us; speedup vs baseline: 1.4486x; 1.4486x over previous
//
#include <hip/hip_runtime.h>

// CausalSelfAttention: B=2, T=4096, E=768, H=12, D=64
// fused prep -> QKV GEMM (m97-style, C^T epilogue) ->
// chunked flash attention (512-kv chunks, kv-step 128, r12-exact, launch_bounds(256,4)) ->
// merge partials -> proj GEMM
// FROZEN LESSONS:
//  - attn body needs ~96 unified regs (64 arch VGPR + 32 AGPR acc). launch_bounds
//    arg 5 or 6 caps below that -> accumulator spill -> 1.3-3.3 GB scratch traffic,
//    2.6-6x regression (r6, r10, r13; VGPR_Count 40/48 signature). ONLY (256,4) works.
//  - r8 (reg-prefetch dbuf) and r9 (no-max softmax) regressed via codegen-induced
//    scratch/remat traffic. Keep the attn dataflow frozen (r12 shape).
//  - r12: kv-step 128 halved barriers, neutral-to-slightly-best (285.66us). Kept.

#define SEQT 4096
#define EMB  768
#define NHEAD 12
#define HDIM 64
#define NCHUNK 144   // sum over qt of ceil((qt+1)/4)

typedef __attribute__((ext_vector_type(8))) short bf16x8;
typedef __attribute__((ext_vector_type(4))) float f32x4;
typedef __attribute__((ext_vector_type(16))) float f32x16;

static __device__ __forceinline__ unsigned short f2bf(float f) {
  union { float f; unsigned u; } a; a.f = f;
  unsigned u = a.u;
  u += 0x7FFF + ((u >> 16) & 1);   // RNE
  return (unsigned short)(u >> 16);
}

// pack two f32 -> bf16x2 {lo=a, hi=b} via HW v_cvt_pk_bf16_f32 (1 op vs 3 for perm path)
static __device__ __forceinline__ unsigned pack_bf16(float a, float b) {
  unsigned r;
  asm("v_cvt_pk_bf16_f32 %0, %1, %2" : "=v"(r) : "v"(a), "v"(b));
  return r;
}

static __device__ __forceinline__ void gload_lds16(const short* g, short* l) {
  __builtin_amdgcn_global_load_lds(
      (const __attribute__((address_space(1))) unsigned*)(const void*)g,
      (__attribute__((address_space(3))) unsigned*)(void*)l, 16, 0, 0);
}

// ---------------- fused prep: cast x -> bf16, transpose W_attn and W_proj ----------------
// grid: [0,6144) cast | [6144,7872) W_attn 72x24 | [7872,8448) W_proj 24x24
__global__ __launch_bounds__(256) void prep_kernel(
    const float* __restrict__ x, short* __restrict__ x_bf,
    const float* __restrict__ W_attn, short* __restrict__ Wt_a,
    const float* __restrict__ W_proj, short* __restrict__ Wt_p) {
  __shared__ float tile[32][33];
  int bid = blockIdx.x;
  int tid = threadIdx.x;
  if (bid < 6144) {
    int i = bid * 256 + tid;     // over 1572864 float4s
    float4 v = ((const float4*)x)[i];
    ushort4 o;
    o.x = f2bf(v.x); o.y = f2bf(v.y); o.z = f2bf(v.z); o.w = f2bf(v.w);
    ((ushort4*)x_bf)[i] = o;
    return;
  }
  const float* in; short* out; int R, C, c0, r0;
  if (bid < 7872) {
    int t = bid - 6144;          // W_attn: [768][2304] -> [2304][768]
    in = W_attn; out = Wt_a; R = 768; C = 2304;
    c0 = (t % 72) * 32; r0 = (t / 72) * 32;
  } else {
    int t = bid - 7872;          // W_proj: [768][768] -> [768][768]
    in = W_proj; out = Wt_p; R = 768; C = 768;
    c0 = (t % 24) * 32; r0 = (t / 24) * 32;
  }
  int tx = tid & 31, ty = tid >> 5;   // 32 x 8
#pragma unroll
  for (int j = 0; j < 32; j += 8)
    tile[ty + j][tx] = in[(size_t)(r0 + ty + j) * C + (c0 + tx)];
  __syncthreads();
#pragma unroll
  for (int j = 0; j < 32; j += 8)
    out[(size_t)(c0 + ty + j) * R + (r0 + tx)] = (short)f2bf(tile[tx][ty + j]);
}

// ---------------- GEMM (m97-style): 128x128 tile, 4 waves, BK=32, global_load_lds ----
// MODE 0: QKV, C^T in regs (mfma(B,A)) -> packed Q/K stores + Vt scatter
// MODE 1: proj, C in regs -> fp32 out [M][768]
template <int MODE>
__global__ __launch_bounds__(256) void gemm128_kernel(
    const short* __restrict__ A, const short* __restrict__ Bt,
    const float* __restrict__ bias, int K,
    short* __restrict__ Qg, short* __restrict__ Kg, short* __restrict__ Vtg,
    float* __restrict__ Out) {
  __shared__ short As[128 * 32];
  __shared__ short Bs[128 * 32];
  int tid = threadIdx.x;
  int w = tid >> 6, l = tid & 63, quad = l >> 4, lo = l & 15;
  int wm = (w >> 1) * 64, wn = (w & 1) * 64;
  int gm = blockIdx.x, gn = blockIdx.y;
  f32x4 acc[4][4] = {};
  int c0 = tid, c1 = tid + 256;   // 16B chunks: row=c>>2, k-sub=(c&3)*8
  const short* Ag0 = A + (size_t)(gm * 128 + (c0 >> 2)) * K + (c0 & 3) * 8;
  const short* Ag1 = A + (size_t)(gm * 128 + (c1 >> 2)) * K + (c1 & 3) * 8;
  const short* Bg0 = Bt + (size_t)(gn * 128 + (c0 >> 2)) * K + (c0 & 3) * 8;
  const short* Bg1 = Bt + (size_t)(gn * 128 + (c1 >> 2)) * K + (c1 & 3) * 8;

  for (int kk = 0; kk < K; kk += 32) {
    gload_lds16(Ag0 + kk, &As[c0 * 8]);
    gload_lds16(Ag1 + kk, &As[c1 * 8]);
    gload_lds16(Bg0 + kk, &Bs[c0 * 8]);
    gload_lds16(Bg1 + kk, &Bs[c1 * 8]);
    __syncthreads();
    bf16x8 af[4], bf[4];
#pragma unroll
    for (int mt = 0; mt < 4; mt++)
      af[mt] = *(const bf16x8*)&As[(wm + mt * 16 + lo) * 32 + quad * 8];
#pragma unroll
    for (int nt = 0; nt < 4; nt++)
      bf[nt] = *(const bf16x8*)&Bs[(wn + nt * 16 + lo) * 32 + quad * 8];
#pragma unroll
    for (int mt = 0; mt < 4; mt++)
#pragma unroll
      for (int nt = 0; nt < 4; nt++) {
        if (MODE == 0)   // C^T: reg-dim = n, lane-dim = m
          acc[mt][nt] = __builtin_amdgcn_mfma_f32_16x16x32_bf16(bf[nt], af[mt], acc[mt][nt], 0, 0, 0);
        else
          acc[mt][nt] = __builtin_amdgcn_mfma_f32_16x16x32_bf16(af[mt], bf[nt], acc[mt][nt], 0, 0, 0);
      }
    __syncthreads();
  }

  if (MODE == 0) {
#pragma unroll
    for (int nt = 0; nt < 4; nt++) {
      int nb = gn * 128 + wn + nt * 16 + quad * 4;   // 4 consecutive n in regs
      float4 bv = *(const float4*)&bias[nb];
#pragma unroll
      for (int mt = 0; mt < 4; mt++) {
        int m = gm * 128 + wm + mt * 16 + lo;
        int b = m >> 12, t = m & 4095;
        float v0 = acc[mt][nt][0] + bv.x;
        float v1 = acc[mt][nt][1] + bv.y;
        float v2 = acc[mt][nt][2] + bv.z;
        float v3 = acc[mt][nt][3] + bv.w;
        if (nb < EMB) {
          int h = nb >> 6, d = nb & 63;
          uint2 u; u.x = pack_bf16(v0, v1); u.y = pack_bf16(v2, v3);
          *(uint2*)&Qg[(((size_t)b * NHEAD + h) * SEQT + t) * HDIM + d] = u;
        } else if (nb < 2 * EMB) {
          int n2 = nb - EMB, h = n2 >> 6, d = n2 & 63;
          uint2 u; u.x = pack_bf16(v0, v1); u.y = pack_bf16(v2, v3);
          *(uint2*)&Kg[(((size_t)b * NHEAD + h) * SEQT + t) * HDIM + d] = u;
        } else {
          int n2 = nb - 2 * EMB, h = n2 >> 6, d = n2 & 63;
          short* vp = &Vtg[(((size_t)b * NHEAD + h) * HDIM + d) * SEQT + t];
          vp[0] = (short)f2bf(v0);
          vp[SEQT] = (short)f2bf(v1);
          vp[2 * SEQT] = (short)f2bf(v2);
          vp[3 * SEQT] = (short)f2bf(v3);
        }
      }
    }
  } else {
#pragma unroll
    for (int nt = 0; nt < 4; nt++) {
      int n = gn * 128 + wn + nt * 16 + lo;
      float bias_v = bias[n];
#pragma unroll
      for (int mt = 0; mt < 4; mt++) {
#pragma unroll
        for (int r = 0; r < 4; r++) {
          int m = gm * 128 + wm + mt * 16 + quad * 4 + r;
          Out[(size_t)m * EMB + n] = acc[mt][nt][r] + bias_v;
        }
      }
    }
  }
}

// ---------------- flash attention (r12-exact): chunked kv, kv-step 128 ----------------
// Grid (144, 24): blockIdx.x = chunk (qt desc, p asc), blockIdx.y = bh.
// Chunk = up to 4 kv-steps of 128 (512 kv); each step = stage 32KB, 1 barrier,
// two 64-kv compute halves, 1 barrier.
// launch_bounds MUST stay (256,4): body needs ~96 unified regs (64 arch + 32 acc);
// (256,5)/(256,6) spill accumulators (r6/r10/r13: VGPR 40/48 signature, GBs of scratch).
#define AP 72     // K rows: 64 d + 8 pad
#define VP 136    // V rows: 128 kv + 8 pad
#define NEG_BIG (-1e9f)
__global__ __launch_bounds__(256, 4) void attn_kernel(
    const short* __restrict__ Qg, const short* __restrict__ Kg,
    const short* __restrict__ Vtg, short* __restrict__ Opart,
    float2* __restrict__ Ml) {
  __shared__ short Ks[128 * AP];   // [kv 128][d 64]
  __shared__ short Vs[64 * VP];    // [d 64][kv 128]
  int tid = threadIdx.x;
  int w = tid >> 6, l = tid & 63;
  int li = l & 31, hi = l >> 5;
  int c = blockIdx.x;
  int bh = blockIdx.y;
  // map c -> (qt desc, p): nc(qt) = ceil((qt+1)/4) = (qt+4)>>2
  int qt = 31, rem = c;
  while (rem >= ((qt + 4) >> 2)) { rem -= (qt + 4) >> 2; qt--; }
  int p = rem;
  int q0 = qt * 128;
  int cid = bh * NCHUNK + c;
  const short* Qbase = Qg + (size_t)bh * SEQT * HDIM;
  const short* Kbase = Kg + (size_t)bh * SEQT * HDIM;
  const short* Vbase = Vtg + (size_t)bh * HDIM * SEQT;

  int qw = q0 + w * 32;            // wave's 32 q rows
  // Q B-frags: n=li -> q=qw+li, k=hi*8+j -> d=kk*16+hi*8+j
  bf16x8 qf[4];
#pragma unroll
  for (int kk = 0; kk < 4; kk++)
    qf[kk] = *(const bf16x8*)&Qbase[(size_t)(qw + li) * HDIM + kk * 16 + hi * 8];

  f32x16 O[2] = {};                // O^T[dt]: d=dt*32+(reg&3)+8*(reg>>2)+4hi, q=qw+li
  float m_s = NEG_BIG;
  float l_s = 0.f;

  int kr = tid >> 1, kc = tid & 1;   // K staging: 128 rows x 2 half-rows (64B)
  int vr = tid >> 2, vc = tid & 3;   // V staging: 64 rows x 4 quarter-rows (64B)
  const float SC = 0.18033688011112042f;   // (1/8) * log2(e)
  int s_begin = 4 * p;
  int s_end = min(4 * p + 4, qt + 1);      // steps of 128 kv

  for (int s = s_begin; s < s_end; s++) {
    int kv0 = s * 128;
    // stage K tile [128 kv][64 d] (4 transient uint4, r7 liveness profile)
    {
      const short* kg = &Kbase[(size_t)(kv0 + kr) * HDIM + kc * 32];
      uint4 a0 = ((const uint4*)kg)[0];
      uint4 a1 = ((const uint4*)kg)[1];
      uint4 a2 = ((const uint4*)kg)[2];
      uint4 a3 = ((const uint4*)kg)[3];
      short* kd = &Ks[kr * AP + kc * 32];
      ((uint4*)kd)[0] = a0; ((uint4*)kd)[1] = a1;
      ((uint4*)kd)[2] = a2; ((uint4*)kd)[3] = a3;
    }
    // stage Vt tile [64 d][128 kv]
    {
      const short* vg = &Vbase[(size_t)vr * SEQT + kv0 + vc * 32];
      uint4 b0 = ((const uint4*)vg)[0];
      uint4 b1 = ((const uint4*)vg)[1];
      uint4 b2 = ((const uint4*)vg)[2];
      uint4 b3 = ((const uint4*)vg)[3];
      short* vd = &Vs[vr * VP + vc * 32];
      ((uint4*)vd)[0] = b0; ((uint4*)vd)[1] = b1;
      ((uint4*)vd)[2] = b2; ((uint4*)vd)[3] = b3;
    }
    __syncthreads();

#pragma unroll
    for (int h2 = 0; h2 < 2; h2++) {
      int kvh = kv0 + h2 * 64;
      if (kvh > qw) break;               // later halves only farther past diagonal
      bool act1 = (kvh + 32 <= qw);
      // K A-frags: m=kv-in-half=li, k=hi*8+j -> d=kk*16+hi*8+j
      bf16x8 ka0[4], ka1[4];
#pragma unroll
      for (int kk = 0; kk < 4; kk++)
        ka0[kk] = *(const bf16x8*)&Ks[(h2 * 64 + li) * AP + kk * 16 + hi * 8];
      if (act1) {
#pragma unroll
        for (int kk = 0; kk < 4; kk++)
          ka1[kk] = *(const bf16x8*)&Ks[(h2 * 64 + 32 + li) * AP + kk * 16 + hi * 8];
      }

      f32x16 st[2];
      {
        f32x16 a = {};
#pragma unroll
        for (int kk = 0; kk < 4; kk++)
          a = __builtin_amdgcn_mfma_f32_32x32x16_bf16(ka0[kk], qf[kk], a, 0, 0, 0);
        st[0] = a;
      }
      if (act1) {
        f32x16 a = {};
#pragma unroll
        for (int kk = 0; kk < 4; kk++)
          a = __builtin_amdgcn_mfma_f32_32x32x16_bf16(ka1[kk], qf[kk], a, 0, 0, 0);
        st[1] = a;
      }

      // online softmax (q = qw+li per lane; kv dim spans regs + hi halves)
      bool full0 = (kvh < qw);
      float mx = NEG_BIG;
      if (full0) {
#pragma unroll
        for (int r = 0; r < 16; r++) mx = fmaxf(mx, st[0][r]);
      } else {                             // diagonal: R <= li-4hi
        int thr = li - 4 * hi;
#pragma unroll
        for (int r = 0; r < 16; r++) {
          const int R = (r & 3) + 8 * (r >> 2);
          st[0][r] = (R <= thr) ? st[0][r] : NEG_BIG;
          mx = fmaxf(mx, st[0][r]);
        }
      }
      if (act1) {
        bool full1 = (kvh + 32 < qw);
        if (full1) {
#pragma unroll
          for (int r = 0; r < 16; r++) mx = fmaxf(mx, st[1][r]);
        } else {
          int thr = li - 4 * hi;           // qw-(kvh+32)=0 on diagonal
#pragma unroll
          for (int r = 0; r < 16; r++) {
            const int R = (r & 3) + 8 * (r >> 2);
            st[1][r] = (R <= thr) ? st[1][r] : NEG_BIG;
            mx = fmaxf(mx, st[1][r]);
          }
        }
      }
      mx = fmaxf(mx, __shfl_xor(mx, 32));
      float mn = fmaxf(m_s, mx);
      float c1 = SC * mn;
      float al = __builtin_amdgcn_exp2f(fminf(SC * m_s - c1, 0.f));
      m_s = mn;
      float sm = 0.f;
      unsigned pk[2][8];
#pragma unroll
      for (int r2 = 0; r2 < 8; r2++) {
        float pa = __builtin_amdgcn_exp2f(fminf(__builtin_fmaf(st[0][2 * r2],     SC, -c1), 0.f));
        float pb = __builtin_amdgcn_exp2f(fminf(__builtin_fmaf(st[0][2 * r2 + 1], SC, -c1), 0.f));
        sm += pa + pb;
        pk[0][r2] = pack_bf16(pa, pb);
      }
      if (act1) {
#pragma unroll
        for (int r2 = 0; r2 < 8; r2++) {
          float pa = __builtin_amdgcn_exp2f(fminf(__builtin_fmaf(st[1][2 * r2],     SC, -c1), 0.f));
          float pb = __builtin_amdgcn_exp2f(fminf(__builtin_fmaf(st[1][2 * r2 + 1], SC, -c1), 0.f));
          sm += pa + pb;
          pk[1][r2] = pack_bf16(pa, pb);
        }
      }
      sm += __shfl_xor(sm, 32);
      l_s = l_s * al + sm;
#pragma unroll
      for (int dt = 0; dt < 2; dt++)
#pragma unroll
        for (int r = 0; r < 16; r++) O[dt][r] *= al;

      // PV: B-frag built in-register from C/D regs; one cross-half exchange
#pragma unroll
      for (int g = 0; g < 4; g++) {
        int t = g >> 1, k2 = g & 1;
        if (t == 1 && !act1) continue;
        unsigned own_a = hi ? pk[t][k2 * 4 + 2] : pk[t][k2 * 4 + 0];
        unsigned own_b = hi ? pk[t][k2 * 4 + 3] : pk[t][k2 * 4 + 1];
        unsigned snd_a = hi ? pk[t][k2 * 4 + 0] : pk[t][k2 * 4 + 2];
        unsigned snd_b = hi ? pk[t][k2 * 4 + 1] : pk[t][k2 * 4 + 3];
        unsigned rcv_a = (unsigned)__shfl_xor((int)snd_a, 32);
        unsigned rcv_b = (unsigned)__shfl_xor((int)snd_b, 32);
        union { unsigned u[4]; bf16x8 v; } pf;
        pf.u[0] = hi ? rcv_a : own_a;
        pf.u[1] = hi ? rcv_b : own_b;
        pf.u[2] = hi ? own_a : rcv_a;
        pf.u[3] = hi ? own_b : rcv_b;
        // V A-frags loaded lazily (short live range); kv offset h2*64 within row
        bf16x8 va0 = *(const bf16x8*)&Vs[li * VP + h2 * 64 + g * 16 + hi * 8];
        bf16x8 va1 = *(const bf16x8*)&Vs[(32 + li) * VP + h2 * 64 + g * 16 + hi * 8];
        O[0] = __builtin_amdgcn_mfma_f32_32x32x16_bf16(va0, pf.v, O[0], 0, 0, 0);
        O[1] = __builtin_amdgcn_mfma_f32_32x32x16_bf16(va1, pf.v, O[1], 0, 0, 0);
      }
    }
    __syncthreads();
  }

  // epilogue: unnormalized O^T partial -> Opart[cid][lq][d] (bf16); (m,l) -> Ml
  int lq = w * 32 + li;
  short* op = &Opart[((size_t)cid * 128 + lq) * 64];
#pragma unroll
  for (int dt = 0; dt < 2; dt++) {
#pragma unroll
    for (int rg = 0; rg < 4; rg++) {
      uint2 u2;
      u2.x = pack_bf16(O[dt][rg * 4 + 0], O[dt][rg * 4 + 1]);
      u2.y = pack_bf16(O[dt][rg * 4 + 2], O[dt][rg * 4 + 3]);
      *(uint2*)(op + dt * 32 + rg * 8 + hi * 4) = u2;
    }
  }
  if (hi == 0) {
    float2 ml; ml.x = m_s; ml.y = l_s;
    Ml[(size_t)cid * 128 + lq] = ml;
  }
}

// ---------------- merge partials ----------------
// Grid (32, 24): qt, bh. 256 thr: lq=tid>>1 (128 q), half=tid&1 (32 d each).
__global__ __launch_bounds__(256) void merge_kernel(
    const short* __restrict__ Opart, const float2* __restrict__ Ml,
    short* __restrict__ Y) {
  int qt = blockIdx.x, bh = blockIdx.y;
  int n = (qt + 4) >> 2;
  int cbase = 0;
  for (int j = qt + 1; j < 32; j++) cbase += (j + 4) >> 2;   // qt-desc layout
  int tid = threadIdx.x;
  int lq = tid >> 1, half = tid & 1;
  int b = bh / NHEAD, h = bh % NHEAD;
  int q = qt * 128 + lq;
  const float SC = 0.18033688011112042f;

  float m_i[8], l_i[8];
  float mstar = NEG_BIG;
#pragma unroll 4
  for (int i = 0; i < n; i++) {
    float2 ml = Ml[((size_t)bh * NCHUNK + cbase + i) * 128 + lq];
    m_i[i] = ml.x; l_i[i] = ml.y;
    mstar = fmaxf(mstar, ml.x);
  }
  float lstar = 0.f;
  float wgt[8];
#pragma unroll 4
  for (int i = 0; i < n; i++) {
    wgt[i] = __builtin_amdgcn_exp2f(fminf(SC * (m_i[i] - mstar), 0.f));
    lstar += l_i[i] * wgt[i];
  }

  float acc[32] = {};
#pragma unroll 4
  for (int i = 0; i < n; i++) {
    const short* op = &Opart[(((size_t)bh * NCHUNK + cbase + i) * 128 + lq) * 64 + half * 32];
    float wi = wgt[i];
#pragma unroll
    for (int v = 0; v < 4; v++) {
      uint4 u = ((const uint4*)op)[v];
      unsigned uu[4] = {u.x, u.y, u.z, u.w};
#pragma unroll
      for (int j = 0; j < 4; j++) {
        union { unsigned u; float f; } lo2, hi2;
        lo2.u = uu[j] << 16;
        hi2.u = uu[j] & 0xFFFF0000u;
        acc[v * 8 + j * 2]     = __builtin_fmaf(lo2.f, wi, acc[v * 8 + j * 2]);
        acc[v * 8 + j * 2 + 1] = __builtin_fmaf(hi2.f, wi, acc[v * 8 + j * 2 + 1]);
      }
    }
  }
  float rl = 1.f / lstar;
  short* yp = &Y[((size_t)b * SEQT + q) * EMB + h * 64 + half * 32];
#pragma unroll
  for (int v = 0; v < 4; v++) {
    uint2 u2;
    u2.x = pack_bf16(acc[v * 8 + 0] * rl, acc[v * 8 + 1] * rl);
    u2.y = pack_bf16(acc[v * 8 + 2] * rl, acc[v * 8 + 3] * rl);
    uint2 u3;
    u3.x = pack_bf16(acc[v * 8 + 4] * rl, acc[v * 8 + 5] * rl);
    u3.y = pack_bf16(acc[v * 8 + 6] * rl, acc[v * 8 + 7] * rl);
    *(uint2*)(yp + v * 8) = u2;
    *(uint2*)(yp + v * 8 + 4) = u3;
  }
}

extern "C" void kernel_launch(void* const* d_in, const int* in_sizes, int n_in,
                              void* d_out, int out_size, void* d_ws, size_t ws_size,
                              hipStream_t stream) {
  const float* x      = (const float*)d_in[0];   // [2,4096,768]
  const float* W_attn = (const float*)d_in[1];   // [768,2304]
  const float* b_attn = (const float*)d_in[2];   // [2304]
  const float* W_proj = (const float*)d_in[3];   // [768,768]
  const float* b_proj = (const float*)d_in[4];   // [768]
  float* out = (float*)d_out;                    // [2,4096,768] fp32

  char* ws = (char*)d_ws;
  short* x_bf  = (short*)(ws + 0);           // 8192x768 bf16
  short* Wt_a  = (short*)(ws + 12582912);    // 2304x768 bf16
  short* Wt_p  = (short*)(ws + 16121856);    // 768x768  bf16
  short* Qg    = (short*)(ws + 17301504);    // [2,12,4096,64]
  short* Kg    = (short*)(ws + 29884416);    // [2,12,4096,64]
  short* Vtg   = (short*)(ws + 42467328);    // [2,12,64,4096]
  short* Ybf   = (short*)(ws + 55050240);    // 8192x768 bf16
  short* Opart = (short*)(ws + 67633152);    // 3456 x 128 x 64 bf16 = 56,623,104 B
  float2* Ml   = (float2*)(ws + 124256256);  // 3456 x 128 float2 = 3,538,944 B
  // total 127,795,200 B

  prep_kernel<<<8448, 256, 0, stream>>>(x, x_bf, W_attn, Wt_a, W_proj, Wt_p);

  gemm128_kernel<0><<<dim3(64, 18), 256, 0, stream>>>(x_bf, Wt_a, b_attn, 768,
                                                      Qg, Kg, Vtg, nullptr);
  attn_kernel<<<dim3(NCHUNK, 24), 256, 0, stream>>>(Qg, Kg, Vtg, Opart, Ml);
  merge_kernel<<<dim3(32, 24), 256, 0, stream>>>(Opart, Ml, Ybf);
  gemm128_kernel<1><<<dim3(64, 6), 256, 0, stream>>>(Ybf, Wt_p, b_proj, 768,
                                                     nullptr, nullptr, nullptr, out);
}

// Round 15
// 281.791 us; speedup vs baseline: 1.7735x; 1.2243x over previous
//
#include <hip/hip_runtime.h>

// CausalSelfAttention: B=2, T=4096, E=768, H=12, D=64
// fused prep -> QKV GEMM (m97-style, C^T epilogue) ->
// chunked flash attention (512-kv chunks, kv-step 128, r12-exact, launch_bounds(256,4)) ->
// merge partials -> proj GEMM
// FROZEN LESSONS:
//  - attn body needs ~96 unified regs (64 arch VGPR + 32 AGPR acc). launch_bounds
//    arg 5 or 6 caps below that -> accumulator spill -> 1.3-3.3 GB scratch traffic
//    (r6, r10, r13; VGPR_Count 40/48 signature). ONLY (256,4) works.
//  - r8 (reg-prefetch dbuf), r9 (no-max softmax), r14 (inline-asm cvt_pk) all
//    regressed via codegen-induced scratch/remat traffic (WRITE_SIZE blowup at
//    constant VGPR_Count). Keep the attn dataflow AND the perm-based pack frozen.
//  - r12: kv-step 128 halved barriers; best config = 285.66us.

#define SEQT 4096
#define EMB  768
#define NHEAD 12
#define HDIM 64
#define NCHUNK 144   // sum over qt of ceil((qt+1)/4)

typedef __attribute__((ext_vector_type(8))) short bf16x8;
typedef __attribute__((ext_vector_type(4))) float f32x4;
typedef __attribute__((ext_vector_type(16))) float f32x16;

static __device__ __forceinline__ unsigned short f2bf(float f) {
  union { float f; unsigned u; } a; a.f = f;
  unsigned u = a.u;
  u += 0x7FFF + ((u >> 16) & 1);   // RNE
  return (unsigned short)(u >> 16);
}

// pack two f32 -> bf16x2 {lo=a, hi=b} via v_perm_b32 (verified r4; r14's inline-asm
// v_cvt_pk_bf16_f32 variant broke the allocator -> 3x WRITE_SIZE, +52% attn time)
static __device__ __forceinline__ unsigned pack_bf16(float a, float b) {
  union { float f; unsigned u; } ua, ub; ua.f = a; ub.f = b;
  return __builtin_amdgcn_perm(ub.u + 0x8000u, ua.u + 0x8000u, 0x07060302u);
}

static __device__ __forceinline__ void gload_lds16(const short* g, short* l) {
  __builtin_amdgcn_global_load_lds(
      (const __attribute__((address_space(1))) unsigned*)(const void*)g,
      (__attribute__((address_space(3))) unsigned*)(void*)l, 16, 0, 0);
}

// ---------------- fused prep: cast x -> bf16, transpose W_attn and W_proj ----------------
// grid: [0,6144) cast | [6144,7872) W_attn 72x24 | [7872,8448) W_proj 24x24
__global__ __launch_bounds__(256) void prep_kernel(
    const float* __restrict__ x, short* __restrict__ x_bf,
    const float* __restrict__ W_attn, short* __restrict__ Wt_a,
    const float* __restrict__ W_proj, short* __restrict__ Wt_p) {
  __shared__ float tile[32][33];
  int bid = blockIdx.x;
  int tid = threadIdx.x;
  if (bid < 6144) {
    int i = bid * 256 + tid;     // over 1572864 float4s
    float4 v = ((const float4*)x)[i];
    ushort4 o;
    o.x = f2bf(v.x); o.y = f2bf(v.y); o.z = f2bf(v.z); o.w = f2bf(v.w);
    ((ushort4*)x_bf)[i] = o;
    return;
  }
  const float* in; short* out; int R, C, c0, r0;
  if (bid < 7872) {
    int t = bid - 6144;          // W_attn: [768][2304] -> [2304][768]
    in = W_attn; out = Wt_a; R = 768; C = 2304;
    c0 = (t % 72) * 32; r0 = (t / 72) * 32;
  } else {
    int t = bid - 7872;          // W_proj: [768][768] -> [768][768]
    in = W_proj; out = Wt_p; R = 768; C = 768;
    c0 = (t % 24) * 32; r0 = (t / 24) * 32;
  }
  int tx = tid & 31, ty = tid >> 5;   // 32 x 8
#pragma unroll
  for (int j = 0; j < 32; j += 8)
    tile[ty + j][tx] = in[(size_t)(r0 + ty + j) * C + (c0 + tx)];
  __syncthreads();
#pragma unroll
  for (int j = 0; j < 32; j += 8)
    out[(size_t)(c0 + ty + j) * R + (r0 + tx)] = (short)f2bf(tile[tx][ty + j]);
}

// ---------------- GEMM (m97-style): 128x128 tile, 4 waves, BK=32, global_load_lds ----
// MODE 0: QKV, C^T in regs (mfma(B,A)) -> packed Q/K stores + Vt scatter
// MODE 1: proj, C in regs -> fp32 out [M][768]
template <int MODE>
__global__ __launch_bounds__(256) void gemm128_kernel(
    const short* __restrict__ A, const short* __restrict__ Bt,
    const float* __restrict__ bias, int K,
    short* __restrict__ Qg, short* __restrict__ Kg, short* __restrict__ Vtg,
    float* __restrict__ Out) {
  __shared__ short As[128 * 32];
  __shared__ short Bs[128 * 32];
  int tid = threadIdx.x;
  int w = tid >> 6, l = tid & 63, quad = l >> 4, lo = l & 15;
  int wm = (w >> 1) * 64, wn = (w & 1) * 64;
  int gm = blockIdx.x, gn = blockIdx.y;
  f32x4 acc[4][4] = {};
  int c0 = tid, c1 = tid + 256;   // 16B chunks: row=c>>2, k-sub=(c&3)*8
  const short* Ag0 = A + (size_t)(gm * 128 + (c0 >> 2)) * K + (c0 & 3) * 8;
  const short* Ag1 = A + (size_t)(gm * 128 + (c1 >> 2)) * K + (c1 & 3) * 8;
  const short* Bg0 = Bt + (size_t)(gn * 128 + (c0 >> 2)) * K + (c0 & 3) * 8;
  const short* Bg1 = Bt + (size_t)(gn * 128 + (c1 >> 2)) * K + (c1 & 3) * 8;

  for (int kk = 0; kk < K; kk += 32) {
    gload_lds16(Ag0 + kk, &As[c0 * 8]);
    gload_lds16(Ag1 + kk, &As[c1 * 8]);
    gload_lds16(Bg0 + kk, &Bs[c0 * 8]);
    gload_lds16(Bg1 + kk, &Bs[c1 * 8]);
    __syncthreads();
    bf16x8 af[4], bf[4];
#pragma unroll
    for (int mt = 0; mt < 4; mt++)
      af[mt] = *(const bf16x8*)&As[(wm + mt * 16 + lo) * 32 + quad * 8];
#pragma unroll
    for (int nt = 0; nt < 4; nt++)
      bf[nt] = *(const bf16x8*)&Bs[(wn + nt * 16 + lo) * 32 + quad * 8];
#pragma unroll
    for (int mt = 0; mt < 4; mt++)
#pragma unroll
      for (int nt = 0; nt < 4; nt++) {
        if (MODE == 0)   // C^T: reg-dim = n, lane-dim = m
          acc[mt][nt] = __builtin_amdgcn_mfma_f32_16x16x32_bf16(bf[nt], af[mt], acc[mt][nt], 0, 0, 0);
        else
          acc[mt][nt] = __builtin_amdgcn_mfma_f32_16x16x32_bf16(af[mt], bf[nt], acc[mt][nt], 0, 0, 0);
      }
    __syncthreads();
  }

  if (MODE == 0) {
#pragma unroll
    for (int nt = 0; nt < 4; nt++) {
      int nb = gn * 128 + wn + nt * 16 + quad * 4;   // 4 consecutive n in regs
      float4 bv = *(const float4*)&bias[nb];
#pragma unroll
      for (int mt = 0; mt < 4; mt++) {
        int m = gm * 128 + wm + mt * 16 + lo;
        int b = m >> 12, t = m & 4095;
        float v0 = acc[mt][nt][0] + bv.x;
        float v1 = acc[mt][nt][1] + bv.y;
        float v2 = acc[mt][nt][2] + bv.z;
        float v3 = acc[mt][nt][3] + bv.w;
        if (nb < EMB) {
          int h = nb >> 6, d = nb & 63;
          uint2 u; u.x = pack_bf16(v0, v1); u.y = pack_bf16(v2, v3);
          *(uint2*)&Qg[(((size_t)b * NHEAD + h) * SEQT + t) * HDIM + d] = u;
        } else if (nb < 2 * EMB) {
          int n2 = nb - EMB, h = n2 >> 6, d = n2 & 63;
          uint2 u; u.x = pack_bf16(v0, v1); u.y = pack_bf16(v2, v3);
          *(uint2*)&Kg[(((size_t)b * NHEAD + h) * SEQT + t) * HDIM + d] = u;
        } else {
          int n2 = nb - 2 * EMB, h = n2 >> 6, d = n2 & 63;
          short* vp = &Vtg[(((size_t)b * NHEAD + h) * HDIM + d) * SEQT + t];
          vp[0] = (short)f2bf(v0);
          vp[SEQT] = (short)f2bf(v1);
          vp[2 * SEQT] = (short)f2bf(v2);
          vp[3 * SEQT] = (short)f2bf(v3);
        }
      }
    }
  } else {
#pragma unroll
    for (int nt = 0; nt < 4; nt++) {
      int n = gn * 128 + wn + nt * 16 + lo;
      float bias_v = bias[n];
#pragma unroll
      for (int mt = 0; mt < 4; mt++) {
#pragma unroll
        for (int r = 0; r < 4; r++) {
          int m = gm * 128 + wm + mt * 16 + quad * 4 + r;
          Out[(size_t)m * EMB + n] = acc[mt][nt][r] + bias_v;
        }
      }
    }
  }
}

// ---------------- flash attention (r12-exact): chunked kv, kv-step 128 ----------------
// Grid (144, 24): blockIdx.x = chunk (qt desc, p asc), blockIdx.y = bh.
// Chunk = up to 4 kv-steps of 128 (512 kv); each step = stage 32KB, 1 barrier,
// two 64-kv compute halves, 1 barrier.
// launch_bounds MUST stay (256,4): body needs ~96 unified regs (64 arch + 32 acc);
// (256,5)/(256,6) spill accumulators (r6/r10/r13: VGPR 40/48 signature, GBs of scratch).
#define AP 72     // K rows: 64 d + 8 pad
#define VP 136    // V rows: 128 kv + 8 pad
#define NEG_BIG (-1e9f)
__global__ __launch_bounds__(256, 4) void attn_kernel(
    const short* __restrict__ Qg, const short* __restrict__ Kg,
    const short* __restrict__ Vtg, short* __restrict__ Opart,
    float2* __restrict__ Ml) {
  __shared__ short Ks[128 * AP];   // [kv 128][d 64]
  __shared__ short Vs[64 * VP];    // [d 64][kv 128]
  int tid = threadIdx.x;
  int w = tid >> 6, l = tid & 63;
  int li = l & 31, hi = l >> 5;
  int c = blockIdx.x;
  int bh = blockIdx.y;
  // map c -> (qt desc, p): nc(qt) = ceil((qt+1)/4) = (qt+4)>>2
  int qt = 31, rem = c;
  while (rem >= ((qt + 4) >> 2)) { rem -= (qt + 4) >> 2; qt--; }
  int p = rem;
  int q0 = qt * 128;
  int cid = bh * NCHUNK + c;
  const short* Qbase = Qg + (size_t)bh * SEQT * HDIM;
  const short* Kbase = Kg + (size_t)bh * SEQT * HDIM;
  const short* Vbase = Vtg + (size_t)bh * HDIM * SEQT;

  int qw = q0 + w * 32;            // wave's 32 q rows
  // Q B-frags: n=li -> q=qw+li, k=hi*8+j -> d=kk*16+hi*8+j
  bf16x8 qf[4];
#pragma unroll
  for (int kk = 0; kk < 4; kk++)
    qf[kk] = *(const bf16x8*)&Qbase[(size_t)(qw + li) * HDIM + kk * 16 + hi * 8];

  f32x16 O[2] = {};                // O^T[dt]: d=dt*32+(reg&3)+8*(reg>>2)+4hi, q=qw+li
  float m_s = NEG_BIG;
  float l_s = 0.f;

  int kr = tid >> 1, kc = tid & 1;   // K staging: 128 rows x 2 half-rows (64B)
  int vr = tid >> 2, vc = tid & 3;   // V staging: 64 rows x 4 quarter-rows (64B)
  const float SC = 0.18033688011112042f;   // (1/8) * log2(e)
  int s_begin = 4 * p;
  int s_end = min(4 * p + 4, qt + 1);      // steps of 128 kv

  for (int s = s_begin; s < s_end; s++) {
    int kv0 = s * 128;
    // stage K tile [128 kv][64 d] (4 transient uint4, r7 liveness profile)
    {
      const short* kg = &Kbase[(size_t)(kv0 + kr) * HDIM + kc * 32];
      uint4 a0 = ((const uint4*)kg)[0];
      uint4 a1 = ((const uint4*)kg)[1];
      uint4 a2 = ((const uint4*)kg)[2];
      uint4 a3 = ((const uint4*)kg)[3];
      short* kd = &Ks[kr * AP + kc * 32];
      ((uint4*)kd)[0] = a0; ((uint4*)kd)[1] = a1;
      ((uint4*)kd)[2] = a2; ((uint4*)kd)[3] = a3;
    }
    // stage Vt tile [64 d][128 kv]
    {
      const short* vg = &Vbase[(size_t)vr * SEQT + kv0 + vc * 32];
      uint4 b0 = ((const uint4*)vg)[0];
      uint4 b1 = ((const uint4*)vg)[1];
      uint4 b2 = ((const uint4*)vg)[2];
      uint4 b3 = ((const uint4*)vg)[3];
      short* vd = &Vs[vr * VP + vc * 32];
      ((uint4*)vd)[0] = b0; ((uint4*)vd)[1] = b1;
      ((uint4*)vd)[2] = b2; ((uint4*)vd)[3] = b3;
    }
    __syncthreads();

#pragma unroll
    for (int h2 = 0; h2 < 2; h2++) {
      int kvh = kv0 + h2 * 64;
      if (kvh > qw) break;               // later halves only farther past diagonal
      bool act1 = (kvh + 32 <= qw);
      // K A-frags: m=kv-in-half=li, k=hi*8+j -> d=kk*16+hi*8+j
      bf16x8 ka0[4], ka1[4];
#pragma unroll
      for (int kk = 0; kk < 4; kk++)
        ka0[kk] = *(const bf16x8*)&Ks[(h2 * 64 + li) * AP + kk * 16 + hi * 8];
      if (act1) {
#pragma unroll
        for (int kk = 0; kk < 4; kk++)
          ka1[kk] = *(const bf16x8*)&Ks[(h2 * 64 + 32 + li) * AP + kk * 16 + hi * 8];
      }

      f32x16 st[2];
      {
        f32x16 a = {};
#pragma unroll
        for (int kk = 0; kk < 4; kk++)
          a = __builtin_amdgcn_mfma_f32_32x32x16_bf16(ka0[kk], qf[kk], a, 0, 0, 0);
        st[0] = a;
      }
      if (act1) {
        f32x16 a = {};
#pragma unroll
        for (int kk = 0; kk < 4; kk++)
          a = __builtin_amdgcn_mfma_f32_32x32x16_bf16(ka1[kk], qf[kk], a, 0, 0, 0);
        st[1] = a;
      }

      // online softmax (q = qw+li per lane; kv dim spans regs + hi halves)
      bool full0 = (kvh < qw);
      float mx = NEG_BIG;
      if (full0) {
#pragma unroll
        for (int r = 0; r < 16; r++) mx = fmaxf(mx, st[0][r]);
      } else {                             // diagonal: R <= li-4hi
        int thr = li - 4 * hi;
#pragma unroll
        for (int r = 0; r < 16; r++) {
          const int R = (r & 3) + 8 * (r >> 2);
          st[0][r] = (R <= thr) ? st[0][r] : NEG_BIG;
          mx = fmaxf(mx, st[0][r]);
        }
      }
      if (act1) {
        bool full1 = (kvh + 32 < qw);
        if (full1) {
#pragma unroll
          for (int r = 0; r < 16; r++) mx = fmaxf(mx, st[1][r]);
        } else {
          int thr = li - 4 * hi;           // qw-(kvh+32)=0 on diagonal
#pragma unroll
          for (int r = 0; r < 16; r++) {
            const int R = (r & 3) + 8 * (r >> 2);
            st[1][r] = (R <= thr) ? st[1][r] : NEG_BIG;
            mx = fmaxf(mx, st[1][r]);
          }
        }
      }
      mx = fmaxf(mx, __shfl_xor(mx, 32));
      float mn = fmaxf(m_s, mx);
      float c1 = SC * mn;
      float al = __builtin_amdgcn_exp2f(fminf(SC * m_s - c1, 0.f));
      m_s = mn;
      float sm = 0.f;
      unsigned pk[2][8];
#pragma unroll
      for (int r2 = 0; r2 < 8; r2++) {
        float pa = __builtin_amdgcn_exp2f(fminf(__builtin_fmaf(st[0][2 * r2],     SC, -c1), 0.f));
        float pb = __builtin_amdgcn_exp2f(fminf(__builtin_fmaf(st[0][2 * r2 + 1], SC, -c1), 0.f));
        sm += pa + pb;
        pk[0][r2] = pack_bf16(pa, pb);
      }
      if (act1) {
#pragma unroll
        for (int r2 = 0; r2 < 8; r2++) {
          float pa = __builtin_amdgcn_exp2f(fminf(__builtin_fmaf(st[1][2 * r2],     SC, -c1), 0.f));
          float pb = __builtin_amdgcn_exp2f(fminf(__builtin_fmaf(st[1][2 * r2 + 1], SC, -c1), 0.f));
          sm += pa + pb;
          pk[1][r2] = pack_bf16(pa, pb);
        }
      }
      sm += __shfl_xor(sm, 32);
      l_s = l_s * al + sm;
#pragma unroll
      for (int dt = 0; dt < 2; dt++)
#pragma unroll
        for (int r = 0; r < 16; r++) O[dt][r] *= al;

      // PV: B-frag built in-register from C/D regs; one cross-half exchange
#pragma unroll
      for (int g = 0; g < 4; g++) {
        int t = g >> 1, k2 = g & 1;
        if (t == 1 && !act1) continue;
        unsigned own_a = hi ? pk[t][k2 * 4 + 2] : pk[t][k2 * 4 + 0];
        unsigned own_b = hi ? pk[t][k2 * 4 + 3] : pk[t][k2 * 4 + 1];
        unsigned snd_a = hi ? pk[t][k2 * 4 + 0] : pk[t][k2 * 4 + 2];
        unsigned snd_b = hi ? pk[t][k2 * 4 + 1] : pk[t][k2 * 4 + 3];
        unsigned rcv_a = (unsigned)__shfl_xor((int)snd_a, 32);
        unsigned rcv_b = (unsigned)__shfl_xor((int)snd_b, 32);
        union { unsigned u[4]; bf16x8 v; } pf;
        pf.u[0] = hi ? rcv_a : own_a;
        pf.u[1] = hi ? rcv_b : own_b;
        pf.u[2] = hi ? own_a : rcv_a;
        pf.u[3] = hi ? own_b : rcv_b;
        // V A-frags loaded lazily (short live range); kv offset h2*64 within row
        bf16x8 va0 = *(const bf16x8*)&Vs[li * VP + h2 * 64 + g * 16 + hi * 8];
        bf16x8 va1 = *(const bf16x8*)&Vs[(32 + li) * VP + h2 * 64 + g * 16 + hi * 8];
        O[0] = __builtin_amdgcn_mfma_f32_32x32x16_bf16(va0, pf.v, O[0], 0, 0, 0);
        O[1] = __builtin_amdgcn_mfma_f32_32x32x16_bf16(va1, pf.v, O[1], 0, 0, 0);
      }
    }
    __syncthreads();
  }

  // epilogue: unnormalized O^T partial -> Opart[cid][lq][d] (bf16); (m,l) -> Ml
  int lq = w * 32 + li;
  short* op = &Opart[((size_t)cid * 128 + lq) * 64];
#pragma unroll
  for (int dt = 0; dt < 2; dt++) {
#pragma unroll
    for (int rg = 0; rg < 4; rg++) {
      uint2 u2;
      u2.x = pack_bf16(O[dt][rg * 4 + 0], O[dt][rg * 4 + 1]);
      u2.y = pack_bf16(O[dt][rg * 4 + 2], O[dt][rg * 4 + 3]);
      *(uint2*)(op + dt * 32 + rg * 8 + hi * 4) = u2;
    }
  }
  if (hi == 0) {
    float2 ml; ml.x = m_s; ml.y = l_s;
    Ml[(size_t)cid * 128 + lq] = ml;
  }
}

// ---------------- merge partials ----------------
// Grid (32, 24): qt, bh. 256 thr: lq=tid>>1 (128 q), half=tid&1 (32 d each).
__global__ __launch_bounds__(256) void merge_kernel(
    const short* __restrict__ Opart, const float2* __restrict__ Ml,
    short* __restrict__ Y) {
  int qt = blockIdx.x, bh = blockIdx.y;
  int n = (qt + 4) >> 2;
  int cbase = 0;
  for (int j = qt + 1; j < 32; j++) cbase += (j + 4) >> 2;   // qt-desc layout
  int tid = threadIdx.x;
  int lq = tid >> 1, half = tid & 1;
  int b = bh / NHEAD, h = bh % NHEAD;
  int q = qt * 128 + lq;
  const float SC = 0.18033688011112042f;

  float m_i[8], l_i[8];
  float mstar = NEG_BIG;
#pragma unroll 4
  for (int i = 0; i < n; i++) {
    float2 ml = Ml[((size_t)bh * NCHUNK + cbase + i) * 128 + lq];
    m_i[i] = ml.x; l_i[i] = ml.y;
    mstar = fmaxf(mstar, ml.x);
  }
  float lstar = 0.f;
  float wgt[8];
#pragma unroll 4
  for (int i = 0; i < n; i++) {
    wgt[i] = __builtin_amdgcn_exp2f(fminf(SC * (m_i[i] - mstar), 0.f));
    lstar += l_i[i] * wgt[i];
  }

  float acc[32] = {};
#pragma unroll 4
  for (int i = 0; i < n; i++) {
    const short* op = &Opart[(((size_t)bh * NCHUNK + cbase + i) * 128 + lq) * 64 + half * 32];
    float wi = wgt[i];
#pragma unroll
    for (int v = 0; v < 4; v++) {
      uint4 u = ((const uint4*)op)[v];
      unsigned uu[4] = {u.x, u.y, u.z, u.w};
#pragma unroll
      for (int j = 0; j < 4; j++) {
        union { unsigned u; float f; } lo2, hi2;
        lo2.u = uu[j] << 16;
        hi2.u = uu[j] & 0xFFFF0000u;
        acc[v * 8 + j * 2]     = __builtin_fmaf(lo2.f, wi, acc[v * 8 + j * 2]);
        acc[v * 8 + j * 2 + 1] = __builtin_fmaf(hi2.f, wi, acc[v * 8 + j * 2 + 1]);
      }
    }
  }
  float rl = 1.f / lstar;
  short* yp = &Y[((size_t)b * SEQT + q) * EMB + h * 64 + half * 32];
#pragma unroll
  for (int v = 0; v < 4; v++) {
    uint2 u2;
    u2.x = pack_bf16(acc[v * 8 + 0] * rl, acc[v * 8 + 1] * rl);
    u2.y = pack_bf16(acc[v * 8 + 2] * rl, acc[v * 8 + 3] * rl);
    uint2 u3;
    u3.x = pack_bf16(acc[v * 8 + 4] * rl, acc[v * 8 + 5] * rl);
    u3.y = pack_bf16(acc[v * 8 + 6] * rl, acc[v * 8 + 7] * rl);
    *(uint2*)(yp + v * 8) = u2;
    *(uint2*)(yp + v * 8 + 4) = u3;
  }
}

extern "C" void kernel_launch(void* const* d_in, const int* in_sizes, int n_in,
                              void* d_out, int out_size, void* d_ws, size_t ws_size,
                              hipStream_t stream) {
  const float* x      = (const float*)d_in[0];   // [2,4096,768]
  const float* W_attn = (const float*)d_in[1];   // [768,2304]
  const float* b_attn = (const float*)d_in[2];   // [2304]
  const float* W_proj = (const float*)d_in[3];   // [768,768]
  const float* b_proj = (const float*)d_in[4];   // [768]
  float* out = (float*)d_out;                    // [2,4096,768] fp32

  char* ws = (char*)d_ws;
  short* x_bf  = (short*)(ws + 0);           // 8192x768 bf16
  short* Wt_a  = (short*)(ws + 12582912);    // 2304x768 bf16
  short* Wt_p  = (short*)(ws + 16121856);    // 768x768  bf16
  short* Qg    = (short*)(ws + 17301504);    // [2,12,4096,64]
  short* Kg    = (short*)(ws + 29884416);    // [2,12,4096,64]
  short* Vtg   = (short*)(ws + 42467328);    // [2,12,64,4096]
  short* Ybf   = (short*)(ws + 55050240);    // 8192x768 bf16
  short* Opart = (short*)(ws + 67633152);    // 3456 x 128 x 64 bf16 = 56,623,104 B
  float2* Ml   = (float2*)(ws + 124256256);  // 3456 x 128 float2 = 3,538,944 B
  // total 127,795,200 B

  prep_kernel<<<8448, 256, 0, stream>>>(x, x_bf, W_attn, Wt_a, W_proj, Wt_p);

  gemm128_kernel<0><<<dim3(64, 18), 256, 0, stream>>>(x_bf, Wt_a, b_attn, 768,
                                                      Qg, Kg, Vtg, nullptr);
  attn_kernel<<<dim3(NCHUNK, 24), 256, 0, stream>>>(Qg, Kg, Vtg, Opart, Ml);
  merge_kernel<<<dim3(32, 24), 256, 0, stream>>>(Opart, Ml, Ybf);
  gemm128_kernel<1><<<dim3(64, 6), 256, 0, stream>>>(Ybf, Wt_p, b_proj, 768,
                                                     nullptr, nullptr, nullptr, out);
}